// Round 5
// baseline (286.834 us; speedup 1.0000x reference)
//
#include <hip/hip_runtime.h>
#include <math.h>

#define NB 16
#define NC 256
#define NHW 1024
#define NE 512
#define NDQ 4
#define NLQ 4
#define NQB 6
#define QDIM 64
#define PIX 16     // pixels per block
#define XPAD 260   // xs row stride (floats)
#define MSP 20     // ms row stride

typedef float v2f __attribute__((ext_vector_type(2)));

// ---- CNOT-ring permutation (compile-time) ----
struct PermT { int v[QDIM]; };
constexpr PermT make_perm() {
    PermT P{};
    int f[QDIM] = {};
    for (int i = 0; i < QDIM; ++i) f[i] = i;
    for (int c = 0; c < NQB; ++c) {
        int t = (c + 1) % NQB;
        for (int i = 0; i < QDIM; ++i)
            if ((f[i] >> (NQB - 1 - c)) & 1) f[i] ^= 1 << (NQB - 1 - t);
    }
    for (int i = 0; i < QDIM; ++i) P.v[f[i]] = i;   // new[i] = old[P.v[i]]
    return P;
}
constexpr PermT PERM = make_perm();

#define ELEM(arr, j) (((j) & 1) ? arr[(j) >> 1].y : arr[(j) >> 1].x)

// ws layout (floats): stats_s[0:512] stats_ss[512:1024] done_u32[1024:1040] A[1056:4128]
#define WS_DONE 1024
#define WS_A    1056
#define WS_ZERO_BYTES ((WS_A + 192 * NB) * 4)

// grid MUST be 1024 blocks: 4 blocks/CU x 256 CU co-resident (barrier relies on it;
// bounded spin + local-recompute fallback keeps it correct even if not).
__global__ __launch_bounds__(256, 4) void k_mega(
    const float* __restrict__ x,
    const float* __restrict__ emb,
    const float* __restrict__ gamma,
    const float* __restrict__ beta,
    const float* __restrict__ w_in,
    const float* __restrict__ b_in,
    const float* __restrict__ theta,
    const float* __restrict__ w_style,
    const float* __restrict__ b_style,
    const float* __restrict__ w_out,
    const float* __restrict__ b_out,
    float* __restrict__ ws,
    float* __restrict__ out) {

    __shared__ float xs[PIX * XPAD];   // [p][c]: normalized h, then raw-x stash; 16.6 KB
    __shared__ float as_[PIX * 36];    // ang [p][o], 2.3 KB
    __shared__ float ms[32 * MSP];     // meas [o][p], 2.5 KB
    __shared__ float mure[32], rsre[32];
    __shared__ float Als[192];         // style+theta table for this image
    __shared__ int s_timeout;

    float* stats_s  = ws;
    float* stats_ss = ws + 512;
    unsigned* doneu = (unsigned*)(ws + WS_DONE);
    float* Ag       = ws + WS_A;

    int blk = blockIdx.x;
    int b = blk >> 6;
    int pbase = (blk & 63) * PIX;
    int t = threadIdx.x;
    int c0 = t >> 2, f4 = (t & 3) * 4;   // 4 channels (c0+64k) x 4 pixels per thread
    int wv = t >> 6;

    // ---- P0: load x tile to registers (the only x read in the pipeline) ----
    float4 xr[4];
    #pragma unroll
    for (int k = 0; k < 4; ++k) {
        int c = c0 + 64 * k;
        xr[k] = *(const float4*)(x + (size_t)(b * NC + c) * NHW + pbase + f4);
    }

    // ---- pre: partial GroupNorm stats from registers ----
    // for slice k, threads [32m,32m+32) all hold channels of group g=(c0>>3)+8k
    #pragma unroll
    for (int k = 0; k < 4; ++k) {
        float4 v = xr[k];
        float s  = v.x + v.y + v.z + v.w;
        float ss = v.x*v.x + v.y*v.y + v.z*v.z + v.w*v.w;
        #pragma unroll
        for (int o = 1; o < 32; o <<= 1) { s += __shfl_xor(s, o); ss += __shfl_xor(ss, o); }
        if ((t & 31) == 0) {
            int g = (c0 >> 3) + 8 * k;
            atomicAdd(&stats_s[b * 32 + g], s);
            atomicAdd(&stats_ss[b * 32 + g], ss);
        }
    }

    // ---- pre: style dots, 3 per block (waves 1..3), j = (blk&63)*3 + wv-1 ----
    if (wv >= 1) {
        int j = (blk & 63) * 3 + (wv - 1);
        int lane = t & 63;
        const float4* er = (const float4*)(emb + (size_t)b * NE + lane * 8);
        const float4* wr = (const float4*)(w_style + (size_t)j * NE + lane * 8);
        float acc = 0.f;
        #pragma unroll
        for (int i = 0; i < 2; ++i) {
            float4 e4 = er[i], w4 = wr[i];
            float s0 = e4.x / (1.f + __expf(-e4.x));
            float s1 = e4.y / (1.f + __expf(-e4.y));
            float s2 = e4.z / (1.f + __expf(-e4.z));
            float s3 = e4.w / (1.f + __expf(-e4.w));
            acc = fmaf(w4.x, s0, fmaf(w4.y, s1, fmaf(w4.z, s2, fmaf(w4.w, s3, acc))));
        }
        #pragma unroll
        for (int o = 1; o < 64; o <<= 1) acc += __shfl_xor(acc, o);
        if (lane == 0) atomicAdd(&Ag[b * 192 + j], acc + theta[j] + b_style[j]);
    }

    __syncthreads();                       // all contributions issued & drained
    if (t == 0) {
        __threadfence();
        atomicAdd(&doneu[b], 1u);
        // spin until all 64 blocks of image b have contributed (bounded)
        int spins = 0, to = 0;
        while (atomicAdd(&doneu[b], 0u) < 64u) {
            if (++spins > 60000) { to = 1; break; }   // ~20 ms cap
            __builtin_amdgcn_s_sleep(8);
        }
        s_timeout = to;
    }
    __syncthreads();
    __threadfence();                       // acquire: see other blocks' results

    if (!s_timeout) {
        // normal path: read shared results via device-scope atomic loads
        if (t < 32) {
            float s  = atomicAdd(&stats_s[b * 32 + t], 0.0f);
            float ss = atomicAdd(&stats_ss[b * 32 + t], 0.0f);
            float m = s * (1.f / 8192.f);
            mure[t] = m;
            rsre[t] = rsqrtf(ss * (1.f / 8192.f) - m * m + 1e-5f);
        }
        if (t < 192) Als[t] = atomicAdd(&Ag[b * 192 + t], 0.0f);
    } else {
        // FALLBACK (correct without any cross-block cooperation):
        // recompute this image's stats and style table locally.
        {   // stats: thread t scans channel t (1024 pixels)
            const float4* row = (const float4*)(x + (size_t)(b * NC + t) * NHW);
            float s = 0.f, ss = 0.f;
            for (int i = 0; i < 256; ++i) {
                float4 v = row[i];
                s  += v.x + v.y + v.z + v.w;
                ss += v.x*v.x + v.y*v.y + v.z*v.z + v.w*v.w;
            }
            #pragma unroll
            for (int o = 1; o < 8; o <<= 1) { s += __shfl_xor(s, o); ss += __shfl_xor(ss, o); }
            if ((t & 7) == 0) {
                int g = t >> 3;
                float m = s * (1.f / 8192.f);
                mure[g] = m;
                rsre[g] = rsqrtf(ss * (1.f / 8192.f) - m * m + 1e-5f);
            }
        }
        if (t < 192) {   // style: full dot per thread
            const float4* er = (const float4*)(emb + (size_t)b * NE);
            const float4* wr = (const float4*)(w_style + (size_t)t * NE);
            float acc = 0.f;
            for (int i = 0; i < 128; ++i) {
                float4 e4 = er[i], w4 = wr[i];
                float s0 = e4.x / (1.f + __expf(-e4.x));
                float s1 = e4.y / (1.f + __expf(-e4.y));
                float s2 = e4.z / (1.f + __expf(-e4.z));
                float s3 = e4.w / (1.f + __expf(-e4.w));
                acc = fmaf(w4.x, s0, fmaf(w4.y, s1, fmaf(w4.z, s2, fmaf(w4.w, s3, acc))));
            }
            Als[t] = acc + theta[t] + b_style[t];
        }
    }
    __syncthreads();

    // ---- P1: normalize regs -> xs [p][c] ----
    #pragma unroll
    for (int k = 0; k < 4; ++k) {
        int c = c0 + 64 * k;
        int g = c >> 3;
        float sc = rsre[g] * gamma[c];
        float sh = fmaf(-mure[g], sc, beta[c]);
        float4 v = xr[k];
        xs[(f4 + 0) * XPAD + c] = fmaf(v.x, sc, sh);
        xs[(f4 + 1) * XPAD + c] = fmaf(v.y, sc, sh);
        xs[(f4 + 2) * XPAD + c] = fmaf(v.z, sc, sh);
        xs[(f4 + 3) * XPAD + c] = fmaf(v.w, sc, sh);
    }
    __syncthreads();

    // ---- P2: ang[p][o] = w_in[o].h[p][:] + b_in[o]; thread = (2 outputs, 1 pixel) ----
    {
        int og2 = t >> 4, p = t & 15;
        int o0 = 2 * og2;
        const float* w0r = w_in + o0 * NC;
        const float* w1r = w_in + (o0 + 1) * NC;
        const float* hrow = xs + p * XPAD;
        float a0 = 0.f, a1 = 0.f;
        #pragma unroll 8
        for (int c = 0; c < NC; c += 4) {
            float4 h = *(const float4*)(hrow + c);
            float4 w0 = *(const float4*)(w0r + c);
            float4 w1 = *(const float4*)(w1r + c);
            a0 = fmaf(w0.x, h.x, fmaf(w0.y, h.y, fmaf(w0.z, h.z, fmaf(w0.w, h.w, a0))));
            a1 = fmaf(w1.x, h.x, fmaf(w1.y, h.y, fmaf(w1.z, h.z, fmaf(w1.w, h.w, a1))));
        }
        as_[p * 36 + o0]     = a0 + b_in[o0];
        as_[p * 36 + o0 + 1] = a1 + b_in[o0 + 1];
    }
    __syncthreads();

    // ---- stash raw x into xs (P2 consumed the normalized copy) ----
    #pragma unroll
    for (int k = 0; k < 4; ++k) {
        int c = c0 + 64 * k;
        float4 v = xr[k];
        xs[(f4 + 0) * XPAD + c] = v.x;
        xs[(f4 + 1) * XPAD + c] = v.y;
        xs[(f4 + 2) * XPAD + c] = v.z;
        xs[(f4 + 3) * XPAD + c] = v.w;
    }

    // ---- P3: circuits, threads 0..127: (g = t>>4, p = t&15) ----
    if (t < 128) {
        int g = t >> 4, p = t & 15;
        float4 angv = *(const float4*)(as_ + p * 36 + g * 4);
        float angp[NDQ] = {angv.x, angv.y, angv.z, angv.w};
        const float* Ab = Als + g * 24;

        v2f st2[QDIM / 2];
        #pragma unroll
        for (int k = 0; k < QDIM / 2; ++k) st2[k] = (v2f){0.f, 0.f};
        st2[0].x = 1.f;

        #pragma unroll
        for (int l = 0; l < NLQ; ++l) {
            #pragma unroll
            for (int q = 0; q < NQB; ++q) {
                float a = Ab[l * NQB + q] + (q < NDQ ? angp[q] : 0.f);
                float sn, cs;
                __sincosf(0.5f * a, &sn, &cs);
                v2f cs2 = {cs, cs};
                if (q < 5) {
                    const int m = 32 >> q;
                    v2f sn2 = {sn, sn};
                    #pragma unroll
                    for (int i = 0; i < QDIM; i += 2) {
                        if (i & m) continue;
                        int klo = i >> 1, khi = (i | m) >> 1;
                        v2f lo = st2[klo], hi = st2[khi];
                        v2f tm = sn2 * hi;
                        v2f um = cs2 * hi;
                        st2[klo] = __builtin_elementwise_fma(cs2, lo, -tm);
                        st2[khi] = __builtin_elementwise_fma(sn2, lo, um);
                    }
                } else {
                    v2f msn = {-sn, sn};
                    #pragma unroll
                    for (int k = 0; k < QDIM / 2; ++k) {
                        v2f a0 = st2[k];
                        v2f asw = __builtin_shufflevector(a0, a0, 1, 0);
                        st2[k] = __builtin_elementwise_fma(msn, asw, cs2 * a0);
                    }
                }
            }
            v2f nst[QDIM / 2];
            #pragma unroll
            for (int k = 0; k < QDIM / 2; ++k) {
                v2f n;
                n.x = ELEM(st2, PERM.v[2 * k]);
                n.y = ELEM(st2, PERM.v[2 * k + 1]);
                nst[k] = n;
            }
            #pragma unroll
            for (int k = 0; k < QDIM / 2; ++k) st2[k] = nst[k];
        }

        float s4[16];
        #pragma unroll
        for (int h = 0; h < 16; ++h) {
            v2f p0 = st2[2 * h] * st2[2 * h];
            v2f p1 = st2[2 * h + 1] * st2[2 * h + 1];
            s4[h] = (p0.x + p0.y) + (p1.x + p1.y);
        }
        float meas[NDQ] = {0.f, 0.f, 0.f, 0.f};
        #pragma unroll
        for (int h = 0; h < 16; ++h) {
            #pragma unroll
            for (int d = 0; d < NDQ; ++d) {
                if ((h >> (3 - d)) & 1) meas[d] -= s4[h];
                else                    meas[d] += s4[h];
            }
        }
        #pragma unroll
        for (int d = 0; d < NDQ; ++d) ms[(g * 4 + d) * MSP + p] = meas[d];
    }
    __syncthreads();

    // ---- P4: out = w_out.meas + b_out + x; thread = (c2 = t>>3, 2 pixels f2) ----
    {
        int c2 = t >> 3, f2 = (t & 7) * 2;
        v2f mreg[32];
        #pragma unroll
        for (int o = 0; o < 32; ++o)
            mreg[o] = *(const v2f*)(ms + o * MSP + f2);
        #pragma unroll
        for (int k = 0; k < 8; ++k) {
            int c = c2 + 32 * k;
            const float* wr = w_out + c * 32;
            float ax = 0.f, ay = 0.f;
            #pragma unroll
            for (int o = 0; o < 32; o += 4) {
                float4 w4 = *(const float4*)(wr + o);
                v2f m0 = mreg[o], m1 = mreg[o+1], m2 = mreg[o+2], m3 = mreg[o+3];
                ax = fmaf(w4.x, m0.x, fmaf(w4.y, m1.x, fmaf(w4.z, m2.x, fmaf(w4.w, m3.x, ax))));
                ay = fmaf(w4.x, m0.y, fmaf(w4.y, m1.y, fmaf(w4.z, m2.y, fmaf(w4.w, m3.y, ay))));
            }
            float bo = b_out[c];
            float x0 = xs[(f2 + 0) * XPAD + c];
            float x1 = xs[(f2 + 1) * XPAD + c];
            float2 r = {ax + bo + x0, ay + bo + x1};
            *(float2*)(out + (size_t)(b * NC + c) * NHW + pbase + f2) = r;
        }
    }
}

extern "C" void kernel_launch(void* const* d_in, const int* in_sizes, int n_in,
                              void* d_out, int out_size, void* d_ws, size_t ws_size,
                              hipStream_t stream) {
    const float* x       = (const float*)d_in[0];
    const float* emb     = (const float*)d_in[1];
    const float* gamma   = (const float*)d_in[2];
    const float* beta    = (const float*)d_in[3];
    const float* w_in    = (const float*)d_in[4];
    const float* b_in    = (const float*)d_in[5];
    const float* theta   = (const float*)d_in[6];
    const float* w_style = (const float*)d_in[7];
    const float* b_style = (const float*)d_in[8];
    const float* w_out   = (const float*)d_in[9];
    const float* b_out   = (const float*)d_in[10];
    float* out = (float*)d_out;
    float* ws = (float*)d_ws;

    // zero stats/done/A accumulators (ws is poisoned 0xAA before every launch)
    hipMemsetAsync(ws, 0, WS_ZERO_BYTES, stream);

    k_mega<<<NB * 64, 256, 0, stream>>>(x, emb, gamma, beta, w_in, b_in, theta,
                                        w_style, b_style, w_out, b_out, ws, out);
}

// Round 6
// 161.230 us; speedup vs baseline: 1.7790x; 1.7790x over previous
//
#include <hip/hip_runtime.h>
#include <math.h>

#define NB 16
#define NC 256
#define NHW 1024
#define NE 512
#define NDQ 4
#define NLQ 4
#define NQB 6
#define QDIM 64
#define PIX 16     // pixels per k_main block
#define XPAD 260   // xs row stride (floats)
#define MSP 20     // ms row stride

typedef float v2f __attribute__((ext_vector_type(2)));

// ---- CNOT-ring permutation (compile-time) ----
struct PermT { int v[QDIM]; };
constexpr PermT make_perm() {
    PermT P{};
    int f[QDIM] = {};
    for (int i = 0; i < QDIM; ++i) f[i] = i;
    for (int c = 0; c < NQB; ++c) {
        int t = (c + 1) % NQB;
        for (int i = 0; i < QDIM; ++i)
            if ((f[i] >> (NQB - 1 - c)) & 1) f[i] ^= 1 << (NQB - 1 - t);
    }
    for (int i = 0; i < QDIM; ++i) P.v[f[i]] = i;   // new[i] = old[P.v[i]]
    return P;
}
constexpr PermT PERM = make_perm();

#define ELEM(arr, j) (((j) & 1) ? arr[(j) >> 1].y : arr[(j) >> 1].x)

// ---- Kernel 1: fused GroupNorm stats (blk<512) + style matvec (blk>=512) ----
__global__ __launch_bounds__(256) void k_pre(const float* __restrict__ x,
                                             const float* __restrict__ emb,
                                             const float* __restrict__ w_style,
                                             const float* __restrict__ b_style,
                                             const float* __restrict__ theta,
                                             float* __restrict__ mu,
                                             float* __restrict__ rs,
                                             float* __restrict__ A) {
    if (blockIdx.x < 512) {
        int bg = blockIdx.x;
        const float4* xp = (const float4*)(x + (size_t)bg * 8 * NHW);
        float s = 0.f, ss = 0.f;
        for (int i = threadIdx.x; i < 8 * NHW / 4; i += 256) {
            float4 v = xp[i];
            s  += v.x + v.y + v.z + v.w;
            ss += v.x*v.x + v.y*v.y + v.z*v.z + v.w*v.w;
        }
        __shared__ float red0[4], red1[4];
        #pragma unroll
        for (int o = 32; o; o >>= 1) { s += __shfl_down(s, o); ss += __shfl_down(ss, o); }
        int lane = threadIdx.x & 63, w = threadIdx.x >> 6;
        if (lane == 0) { red0[w] = s; red1[w] = ss; }
        __syncthreads();
        if (threadIdx.x == 0) {
            s  = red0[0] + red0[1] + red0[2] + red0[3];
            ss = red1[0] + red1[1] + red1[2] + red1[3];
            float m = s * (1.f / 8192.f);
            float var = ss * (1.f / 8192.f) - m * m;
            mu[bg] = m;
            rs[bg] = rsqrtf(var + 1e-5f);
        }
    } else {
        int b = blockIdx.x - 512;
        __shared__ float es[NE];
        int t = threadIdx.x;
        for (int i = t; i < NE; i += 256) {
            float v = emb[b * NE + i];
            es[i] = v / (1.f + __expf(-v));
        }
        __syncthreads();
        int j0 = t >> 3, sub = t & 7;
        for (int pass = 0; pass < 6; ++pass) {
            int j = pass * 32 + j0;
            const float* wr = w_style + (size_t)j * NE + sub * 64;
            const float* er = es + sub * 64;
            float acc = 0.f;
            #pragma unroll
            for (int i = 0; i < 64; i += 4) {
                float4 w4 = *(const float4*)(wr + i);
                acc = fmaf(w4.x, er[i],   acc);
                acc = fmaf(w4.y, er[i+1], acc);
                acc = fmaf(w4.z, er[i+2], acc);
                acc = fmaf(w4.w, er[i+3], acc);
            }
            acc += __shfl_xor(acc, 1);
            acc += __shfl_xor(acc, 2);
            acc += __shfl_xor(acc, 4);
            if (sub == 0) A[b * 192 + j] = theta[j] + b_style[j] + acc;
        }
    }
}

// ---- Kernel 2: fused main. grid = 1024 blocks x 128 thr, PIX=16, ~7 blk/CU ----
__global__ __launch_bounds__(128, 4) void k_main(
    const float* __restrict__ x,
    const float* __restrict__ gamma,
    const float* __restrict__ beta,
    const float* __restrict__ w_in,
    const float* __restrict__ b_in,
    const float* __restrict__ A,
    const float* __restrict__ w_out,
    const float* __restrict__ b_out,
    const float* __restrict__ mu,
    const float* __restrict__ rs,
    float* __restrict__ out) {

    __shared__ float xs[PIX * XPAD];   // [p][c]: normalized h, then raw-x stash; 16.6 KB
    __shared__ float as_[PIX * 36];    // ang [p][o], 2.3 KB
    __shared__ float ms[32 * MSP];     // meas [o][p], 2.5 KB

    int blk = blockIdx.x;
    int b = blk >> 6;
    int pbase = (blk & 63) * PIX;
    int t = threadIdx.x;
    int c0 = t >> 2, f4 = (t & 3) * 4;   // thread owns channels c0+32k (k<8) x 4 pixels

    // ---- P0: load x tile to registers (the only x read in this kernel) ----
    float4 xr[8];
    #pragma unroll
    for (int k = 0; k < 8; ++k) {
        int c = c0 + 32 * k;
        xr[k] = *(const float4*)(x + (size_t)(b * NC + c) * NHW + pbase + f4);
    }

    // ---- P1: normalize -> xs [p][c] (scale/shift computed inline, L1-broadcast) ----
    #pragma unroll
    for (int k = 0; k < 8; ++k) {
        int c = c0 + 32 * k;
        int g = b * 32 + (c >> 3);
        float sc = rs[g] * gamma[c];
        float sh = fmaf(-mu[g], sc, beta[c]);
        float4 v = xr[k];
        xs[(f4 + 0) * XPAD + c] = fmaf(v.x, sc, sh);
        xs[(f4 + 1) * XPAD + c] = fmaf(v.y, sc, sh);
        xs[(f4 + 2) * XPAD + c] = fmaf(v.z, sc, sh);
        xs[(f4 + 3) * XPAD + c] = fmaf(v.w, sc, sh);
    }
    __syncthreads();

    // ---- P2: ang[p][o]; thread = (4 outputs, 1 pixel) -> 1 h-row read per 4 dots ----
    {
        int og = t >> 4, p = t & 15;
        int o0 = og * 4;
        const float* wbase = w_in + o0 * NC;
        const float* hrow = xs + p * XPAD;
        float a0 = 0.f, a1 = 0.f, a2 = 0.f, a3 = 0.f;
        #pragma unroll 8
        for (int c = 0; c < NC; c += 4) {
            float4 h = *(const float4*)(hrow + c);
            float4 w0 = *(const float4*)(wbase + c);
            float4 w1 = *(const float4*)(wbase + NC + c);
            float4 w2 = *(const float4*)(wbase + 2 * NC + c);
            float4 w3 = *(const float4*)(wbase + 3 * NC + c);
            a0 = fmaf(w0.x, h.x, fmaf(w0.y, h.y, fmaf(w0.z, h.z, fmaf(w0.w, h.w, a0))));
            a1 = fmaf(w1.x, h.x, fmaf(w1.y, h.y, fmaf(w1.z, h.z, fmaf(w1.w, h.w, a1))));
            a2 = fmaf(w2.x, h.x, fmaf(w2.y, h.y, fmaf(w2.z, h.z, fmaf(w2.w, h.w, a2))));
            a3 = fmaf(w3.x, h.x, fmaf(w3.y, h.y, fmaf(w3.z, h.z, fmaf(w3.w, h.w, a3))));
        }
        float4 bi = *(const float4*)(b_in + o0);
        float4 r = {a0 + bi.x, a1 + bi.y, a2 + bi.z, a3 + bi.w};
        *(float4*)(as_ + p * 36 + o0) = r;
    }
    __syncthreads();

    // ---- stash raw x into xs (P2 consumed the normalized copy); frees xr regs ----
    #pragma unroll
    for (int k = 0; k < 8; ++k) {
        int c = c0 + 32 * k;
        float4 v = xr[k];
        xs[(f4 + 0) * XPAD + c] = v.x;
        xs[(f4 + 1) * XPAD + c] = v.y;
        xs[(f4 + 2) * XPAD + c] = v.z;
        xs[(f4 + 3) * XPAD + c] = v.w;
    }

    // ---- P3: circuits — ALL 128 threads: (g = t>>4, p = t&15) ----
    {
        int g = t >> 4, p = t & 15;
        float4 angv = *(const float4*)(as_ + p * 36 + g * 4);
        float angp[NDQ] = {angv.x, angv.y, angv.z, angv.w};
        float Ar[24];
        {
            const float4* Ab4 = (const float4*)(A + b * 192 + g * 24);
            #pragma unroll
            for (int j = 0; j < 6; ++j) {
                float4 a4 = Ab4[j];
                Ar[4*j] = a4.x; Ar[4*j+1] = a4.y; Ar[4*j+2] = a4.z; Ar[4*j+3] = a4.w;
            }
        }

        v2f st2[QDIM / 2];
        #pragma unroll
        for (int k = 0; k < QDIM / 2; ++k) st2[k] = (v2f){0.f, 0.f};
        st2[0].x = 1.f;

        #pragma unroll
        for (int l = 0; l < NLQ; ++l) {
            #pragma unroll
            for (int q = 0; q < NQB; ++q) {
                float a = Ar[l * NQB + q] + (q < NDQ ? angp[q] : 0.f);
                float sn, cs;
                __sincosf(0.5f * a, &sn, &cs);
                v2f cs2 = {cs, cs};
                if (q < 5) {
                    const int m = 32 >> q;
                    v2f sn2 = {sn, sn};
                    #pragma unroll
                    for (int i = 0; i < QDIM; i += 2) {
                        if (i & m) continue;
                        int klo = i >> 1, khi = (i | m) >> 1;
                        v2f lo = st2[klo], hi = st2[khi];
                        v2f tm = sn2 * hi;
                        v2f um = cs2 * hi;
                        st2[klo] = __builtin_elementwise_fma(cs2, lo, -tm);
                        st2[khi] = __builtin_elementwise_fma(sn2, lo, um);
                    }
                } else {
                    v2f msn = {-sn, sn};
                    #pragma unroll
                    for (int k = 0; k < QDIM / 2; ++k) {
                        v2f a0 = st2[k];
                        v2f asw = __builtin_shufflevector(a0, a0, 1, 0);
                        st2[k] = __builtin_elementwise_fma(msn, asw, cs2 * a0);
                    }
                }
            }
            v2f nst[QDIM / 2];
            #pragma unroll
            for (int k = 0; k < QDIM / 2; ++k) {
                v2f n;
                n.x = ELEM(st2, PERM.v[2 * k]);
                n.y = ELEM(st2, PERM.v[2 * k + 1]);
                nst[k] = n;
            }
            #pragma unroll
            for (int k = 0; k < QDIM / 2; ++k) st2[k] = nst[k];
        }

        float s4[16];
        #pragma unroll
        for (int h = 0; h < 16; ++h) {
            v2f p0 = st2[2 * h] * st2[2 * h];
            v2f p1 = st2[2 * h + 1] * st2[2 * h + 1];
            s4[h] = (p0.x + p0.y) + (p1.x + p1.y);
        }
        float meas[NDQ] = {0.f, 0.f, 0.f, 0.f};
        #pragma unroll
        for (int h = 0; h < 16; ++h) {
            #pragma unroll
            for (int d = 0; d < NDQ; ++d) {
                if ((h >> (3 - d)) & 1) meas[d] -= s4[h];
                else                    meas[d] += s4[h];
            }
        }
        #pragma unroll
        for (int d = 0; d < NDQ; ++d) ms[(g * 4 + d) * MSP + p] = meas[d];
    }
    __syncthreads();

    // ---- P4: out = w_out.meas + b_out + x; thread = (16 channels, 2 pixels) ----
    {
        int c2 = t >> 3, f2 = (t & 7) * 2;
        v2f mreg[32];
        #pragma unroll
        for (int o = 0; o < 32; ++o)
            mreg[o] = *(const v2f*)(ms + o * MSP + f2);
        #pragma unroll
        for (int k = 0; k < 16; ++k) {
            int c = c2 + 16 * k;
            const float* wr = w_out + c * 32;
            float ax = 0.f, ay = 0.f;
            #pragma unroll
            for (int o = 0; o < 32; o += 4) {
                float4 w4 = *(const float4*)(wr + o);
                v2f m0 = mreg[o], m1 = mreg[o+1], m2 = mreg[o+2], m3 = mreg[o+3];
                ax = fmaf(w4.x, m0.x, fmaf(w4.y, m1.x, fmaf(w4.z, m2.x, fmaf(w4.w, m3.x, ax))));
                ay = fmaf(w4.x, m0.y, fmaf(w4.y, m1.y, fmaf(w4.z, m2.y, fmaf(w4.w, m3.y, ay))));
            }
            float bo = b_out[c];
            float x0 = xs[(f2 + 0) * XPAD + c];
            float x1 = xs[(f2 + 1) * XPAD + c];
            float2 r = {ax + bo + x0, ay + bo + x1};
            *(float2*)(out + (size_t)(b * NC + c) * NHW + pbase + f2) = r;
        }
    }
}

extern "C" void kernel_launch(void* const* d_in, const int* in_sizes, int n_in,
                              void* d_out, int out_size, void* d_ws, size_t ws_size,
                              hipStream_t stream) {
    const float* x       = (const float*)d_in[0];
    const float* emb     = (const float*)d_in[1];
    const float* gamma   = (const float*)d_in[2];
    const float* beta    = (const float*)d_in[3];
    const float* w_in    = (const float*)d_in[4];
    const float* b_in    = (const float*)d_in[5];
    const float* theta   = (const float*)d_in[6];
    const float* w_style = (const float*)d_in[7];
    const float* b_style = (const float*)d_in[8];
    const float* w_out   = (const float*)d_in[9];
    const float* b_out   = (const float*)d_in[10];
    float* out = (float*)d_out;

    float* ws = (float*)d_ws;
    float* mu = ws;           // 512
    float* rs = ws + 512;     // 512
    float* A  = ws + 1024;    // 3072

    k_pre<<<512 + NB, 256, 0, stream>>>(x, emb, w_style, b_style, theta, mu, rs, A);
    k_main<<<NB * 64, 128, 0, stream>>>(x, gamma, beta, w_in, b_in, A,
                                        w_out, b_out, mu, rs, out);
}

// Round 7
// 137.526 us; speedup vs baseline: 2.0857x; 1.1724x over previous
//
#include <hip/hip_runtime.h>
#include <math.h>

#define NB 16
#define NC 256
#define NHW 1024
#define NE 512
#define NDQ 4
#define NLQ 4
#define NQB 6
#define QDIM 64
#define PIX 16     // pixels per k_main block
#define XPAD 260   // xs row stride (floats)
#define MSP 20     // ms row stride

typedef float v2f __attribute__((ext_vector_type(2)));

// ---- CNOT-ring permutation (compile-time) ----
struct PermT { int v[QDIM]; };
constexpr PermT make_perm() {
    PermT P{};
    int f[QDIM] = {};
    for (int i = 0; i < QDIM; ++i) f[i] = i;
    for (int c = 0; c < NQB; ++c) {
        int t = (c + 1) % NQB;
        for (int i = 0; i < QDIM; ++i)
            if ((f[i] >> (NQB - 1 - c)) & 1) f[i] ^= 1 << (NQB - 1 - t);
    }
    for (int i = 0; i < QDIM; ++i) P.v[f[i]] = i;   // new[i] = old[P.v[i]]
    return P;
}
constexpr PermT PERM = make_perm();

#define ELEM(arr, j) (((j) & 1) ? arr[(j) >> 1].y : arr[(j) >> 1].x)

// ---- Kernel 1: fused GroupNorm stats (blk<512) + style matvec (blk>=512) ----
__global__ __launch_bounds__(256) void k_pre(const float* __restrict__ x,
                                             const float* __restrict__ emb,
                                             const float* __restrict__ w_style,
                                             const float* __restrict__ b_style,
                                             const float* __restrict__ theta,
                                             float* __restrict__ mu,
                                             float* __restrict__ rs,
                                             float* __restrict__ A) {
    if (blockIdx.x < 512) {
        int bg = blockIdx.x;
        const float4* xp = (const float4*)(x + (size_t)bg * 8 * NHW);
        float s = 0.f, ss = 0.f;
        for (int i = threadIdx.x; i < 8 * NHW / 4; i += 256) {
            float4 v = xp[i];
            s  += v.x + v.y + v.z + v.w;
            ss += v.x*v.x + v.y*v.y + v.z*v.z + v.w*v.w;
        }
        __shared__ float red0[4], red1[4];
        #pragma unroll
        for (int o = 32; o; o >>= 1) { s += __shfl_down(s, o); ss += __shfl_down(ss, o); }
        int lane = threadIdx.x & 63, w = threadIdx.x >> 6;
        if (lane == 0) { red0[w] = s; red1[w] = ss; }
        __syncthreads();
        if (threadIdx.x == 0) {
            s  = red0[0] + red0[1] + red0[2] + red0[3];
            ss = red1[0] + red1[1] + red1[2] + red1[3];
            float m = s * (1.f / 8192.f);
            float var = ss * (1.f / 8192.f) - m * m;
            mu[bg] = m;
            rs[bg] = rsqrtf(var + 1e-5f);
        }
    } else {
        int b = blockIdx.x - 512;
        __shared__ float es[NE];
        int t = threadIdx.x;
        for (int i = t; i < NE; i += 256) {
            float v = emb[b * NE + i];
            es[i] = v / (1.f + __expf(-v));
        }
        __syncthreads();
        int j0 = t >> 3, sub = t & 7;
        for (int pass = 0; pass < 6; ++pass) {
            int j = pass * 32 + j0;
            const float* wr = w_style + (size_t)j * NE + sub * 64;
            const float* er = es + sub * 64;
            float acc = 0.f;
            #pragma unroll
            for (int i = 0; i < 64; i += 4) {
                float4 w4 = *(const float4*)(wr + i);
                acc = fmaf(w4.x, er[i],   acc);
                acc = fmaf(w4.y, er[i+1], acc);
                acc = fmaf(w4.z, er[i+2], acc);
                acc = fmaf(w4.w, er[i+3], acc);
            }
            acc += __shfl_xor(acc, 1);
            acc += __shfl_xor(acc, 2);
            acc += __shfl_xor(acc, 4);
            if (sub == 0) A[b * 192 + j] = theta[j] + b_style[j] + acc;
        }
    }
}

// ---- Kernel 2: fused main. grid = 1024 blocks x 128 thr, PIX=16 ----
// launch_bounds (128,2): VGPR cap 256 -> NO SPILL (R6's (128,4) forced 64 VGPR
// and 40 MB of scratch spill traffic). LDS 21.5 KB caps residency at 7 blk/CU.
__global__ __launch_bounds__(128, 2) void k_main(
    const float* __restrict__ x,
    const float* __restrict__ gamma,
    const float* __restrict__ beta,
    const float* __restrict__ w_in,
    const float* __restrict__ b_in,
    const float* __restrict__ A,
    const float* __restrict__ w_out,
    const float* __restrict__ b_out,
    const float* __restrict__ mu,
    const float* __restrict__ rs,
    float* __restrict__ out) {

    __shared__ float xs[PIX * XPAD];   // [p][c]: normalized h, then raw-x stash; 16.6 KB
    __shared__ float as_[PIX * 36];    // ang [p][o], 2.3 KB
    __shared__ float ms[32 * MSP];     // meas [o][p], 2.5 KB

    int blk = blockIdx.x;
    int b = blk >> 6;
    int pbase = (blk & 63) * PIX;
    int t = threadIdx.x;
    int c0 = t >> 2, f4 = (t & 3) * 4;   // thread owns channels c0+32k (k<8) x 4 pixels

    // ---- P0: load x tile to registers (the only x read in this kernel) ----
    float4 xr[8];
    #pragma unroll
    for (int k = 0; k < 8; ++k) {
        int c = c0 + 32 * k;
        xr[k] = *(const float4*)(x + (size_t)(b * NC + c) * NHW + pbase + f4);
    }

    // ---- P1: normalize -> xs [p][c] (scale/shift computed inline, L1-broadcast) ----
    #pragma unroll
    for (int k = 0; k < 8; ++k) {
        int c = c0 + 32 * k;
        int g = b * 32 + (c >> 3);
        float sc = rs[g] * gamma[c];
        float sh = fmaf(-mu[g], sc, beta[c]);
        float4 v = xr[k];
        xs[(f4 + 0) * XPAD + c] = fmaf(v.x, sc, sh);
        xs[(f4 + 1) * XPAD + c] = fmaf(v.y, sc, sh);
        xs[(f4 + 2) * XPAD + c] = fmaf(v.z, sc, sh);
        xs[(f4 + 3) * XPAD + c] = fmaf(v.w, sc, sh);
    }
    __syncthreads();

    // ---- P2: ang[p][o]; thread = (4 outputs, 1 pixel) -> 1 h-row read per 4 dots ----
    {
        int og = t >> 4, p = t & 15;
        int o0 = og * 4;
        const float* wbase = w_in + o0 * NC;
        const float* hrow = xs + p * XPAD;
        float a0 = 0.f, a1 = 0.f, a2 = 0.f, a3 = 0.f;
        #pragma unroll 8
        for (int c = 0; c < NC; c += 4) {
            float4 h = *(const float4*)(hrow + c);
            float4 w0 = *(const float4*)(wbase + c);
            float4 w1 = *(const float4*)(wbase + NC + c);
            float4 w2 = *(const float4*)(wbase + 2 * NC + c);
            float4 w3 = *(const float4*)(wbase + 3 * NC + c);
            a0 = fmaf(w0.x, h.x, fmaf(w0.y, h.y, fmaf(w0.z, h.z, fmaf(w0.w, h.w, a0))));
            a1 = fmaf(w1.x, h.x, fmaf(w1.y, h.y, fmaf(w1.z, h.z, fmaf(w1.w, h.w, a1))));
            a2 = fmaf(w2.x, h.x, fmaf(w2.y, h.y, fmaf(w2.z, h.z, fmaf(w2.w, h.w, a2))));
            a3 = fmaf(w3.x, h.x, fmaf(w3.y, h.y, fmaf(w3.z, h.z, fmaf(w3.w, h.w, a3))));
        }
        float4 bi = *(const float4*)(b_in + o0);
        float4 r = {a0 + bi.x, a1 + bi.y, a2 + bi.z, a3 + bi.w};
        *(float4*)(as_ + p * 36 + o0) = r;
    }
    __syncthreads();

    // ---- stash raw x into xs (P2 consumed the normalized copy); frees xr regs ----
    #pragma unroll
    for (int k = 0; k < 8; ++k) {
        int c = c0 + 32 * k;
        float4 v = xr[k];
        xs[(f4 + 0) * XPAD + c] = v.x;
        xs[(f4 + 1) * XPAD + c] = v.y;
        xs[(f4 + 2) * XPAD + c] = v.z;
        xs[(f4 + 3) * XPAD + c] = v.w;
    }

    // ---- P3: circuits — ALL 128 threads: (g = t>>4, p = t&15) ----
    {
        int g = t >> 4, p = t & 15;
        float4 angv = *(const float4*)(as_ + p * 36 + g * 4);
        float angp[NDQ] = {angv.x, angv.y, angv.z, angv.w};
        float Ar[24];
        {
            const float4* Ab4 = (const float4*)(A + b * 192 + g * 24);
            #pragma unroll
            for (int j = 0; j < 6; ++j) {
                float4 a4 = Ab4[j];
                Ar[4*j] = a4.x; Ar[4*j+1] = a4.y; Ar[4*j+2] = a4.z; Ar[4*j+3] = a4.w;
            }
        }

        v2f st2[QDIM / 2];
        #pragma unroll
        for (int k = 0; k < QDIM / 2; ++k) st2[k] = (v2f){0.f, 0.f};
        st2[0].x = 1.f;

        #pragma unroll
        for (int l = 0; l < NLQ; ++l) {
            #pragma unroll
            for (int q = 0; q < NQB; ++q) {
                float a = Ar[l * NQB + q] + (q < NDQ ? angp[q] : 0.f);
                float sn, cs;
                __sincosf(0.5f * a, &sn, &cs);
                v2f cs2 = {cs, cs};
                if (q < 5) {
                    const int m = 32 >> q;
                    v2f sn2 = {sn, sn};
                    #pragma unroll
                    for (int i = 0; i < QDIM; i += 2) {
                        if (i & m) continue;
                        int klo = i >> 1, khi = (i | m) >> 1;
                        v2f lo = st2[klo], hi = st2[khi];
                        v2f tm = sn2 * hi;
                        v2f um = cs2 * hi;
                        st2[klo] = __builtin_elementwise_fma(cs2, lo, -tm);
                        st2[khi] = __builtin_elementwise_fma(sn2, lo, um);
                    }
                } else {
                    v2f msn = {-sn, sn};
                    #pragma unroll
                    for (int k = 0; k < QDIM / 2; ++k) {
                        v2f a0 = st2[k];
                        v2f asw = __builtin_shufflevector(a0, a0, 1, 0);
                        st2[k] = __builtin_elementwise_fma(msn, asw, cs2 * a0);
                    }
                }
            }
            v2f nst[QDIM / 2];
            #pragma unroll
            for (int k = 0; k < QDIM / 2; ++k) {
                v2f n;
                n.x = ELEM(st2, PERM.v[2 * k]);
                n.y = ELEM(st2, PERM.v[2 * k + 1]);
                nst[k] = n;
            }
            #pragma unroll
            for (int k = 0; k < QDIM / 2; ++k) st2[k] = nst[k];
        }

        float s4[16];
        #pragma unroll
        for (int h = 0; h < 16; ++h) {
            v2f p0 = st2[2 * h] * st2[2 * h];
            v2f p1 = st2[2 * h + 1] * st2[2 * h + 1];
            s4[h] = (p0.x + p0.y) + (p1.x + p1.y);
        }
        float meas[NDQ] = {0.f, 0.f, 0.f, 0.f};
        #pragma unroll
        for (int h = 0; h < 16; ++h) {
            #pragma unroll
            for (int d = 0; d < NDQ; ++d) {
                if ((h >> (3 - d)) & 1) meas[d] -= s4[h];
                else                    meas[d] += s4[h];
            }
        }
        #pragma unroll
        for (int d = 0; d < NDQ; ++d) ms[(g * 4 + d) * MSP + p] = meas[d];
    }
    __syncthreads();

    // ---- P4: out = w_out.meas + b_out + x; thread = (16 channels, 2 pixels) ----
    {
        int c2 = t >> 3, f2 = (t & 7) * 2;
        v2f mreg[32];
        #pragma unroll
        for (int o = 0; o < 32; ++o)
            mreg[o] = *(const v2f*)(ms + o * MSP + f2);
        #pragma unroll
        for (int k = 0; k < 16; ++k) {
            int c = c2 + 16 * k;
            const float* wr = w_out + c * 32;
            float ax = 0.f, ay = 0.f;
            #pragma unroll
            for (int o = 0; o < 32; o += 4) {
                float4 w4 = *(const float4*)(wr + o);
                v2f m0 = mreg[o], m1 = mreg[o+1], m2 = mreg[o+2], m3 = mreg[o+3];
                ax = fmaf(w4.x, m0.x, fmaf(w4.y, m1.x, fmaf(w4.z, m2.x, fmaf(w4.w, m3.x, ax))));
                ay = fmaf(w4.x, m0.y, fmaf(w4.y, m1.y, fmaf(w4.z, m2.y, fmaf(w4.w, m3.y, ay))));
            }
            float bo = b_out[c];
            float x0 = xs[(f2 + 0) * XPAD + c];
            float x1 = xs[(f2 + 1) * XPAD + c];
            float2 r = {ax + bo + x0, ay + bo + x1};
            *(float2*)(out + (size_t)(b * NC + c) * NHW + pbase + f2) = r;
        }
    }
}

extern "C" void kernel_launch(void* const* d_in, const int* in_sizes, int n_in,
                              void* d_out, int out_size, void* d_ws, size_t ws_size,
                              hipStream_t stream) {
    const float* x       = (const float*)d_in[0];
    const float* emb     = (const float*)d_in[1];
    const float* gamma   = (const float*)d_in[2];
    const float* beta    = (const float*)d_in[3];
    const float* w_in    = (const float*)d_in[4];
    const float* b_in    = (const float*)d_in[5];
    const float* theta   = (const float*)d_in[6];
    const float* w_style = (const float*)d_in[7];
    const float* b_style = (const float*)d_in[8];
    const float* w_out   = (const float*)d_in[9];
    const float* b_out   = (const float*)d_in[10];
    float* out = (float*)d_out;

    float* ws = (float*)d_ws;
    float* mu = ws;           // 512
    float* rs = ws + 512;     // 512
    float* A  = ws + 1024;    // 3072

    k_pre<<<512 + NB, 256, 0, stream>>>(x, emb, w_style, b_style, theta, mu, rs, A);
    k_main<<<NB * 64, 128, 0, stream>>>(x, gamma, beta, w_in, b_in, A,
                                        w_out, b_out, mu, rs, out);
}